// Round 9
// baseline (133.113 us; speedup 1.0000x reference)
//
#include <hip/hip_runtime.h>
#include <hip/hip_bf16.h>
#include <math.h>

// MultiAttention  B=8, T=2048, D=100, H=2, K=50
// out = x + attn(x) @ Wo + bo; scores += mask[(b*2+h)%8][s].
// R9: 64 q-rows per wave (4 sets of 16) -> each 16-frag K/V fetch feeds 64
// MFMAs (2x arithmetic intensity of R8); 4 independent per-set chains give
// intra-wave ILP to hide the QK->exp2->LDS->PV latency chain. Max-free exp2
// softmax, DPP-packed P writes, frag-order layouts as R8.

#define BATCH 8
#define SEQ   2048
#define DIN   100
#define NH    2
#define KR    50
#define KD    64
#define BH    16
#define LOG2E 1.44269504f

typedef __attribute__((ext_vector_type(8))) short short8;
typedef __attribute__((ext_vector_type(4))) float float4v;
typedef __attribute__((ext_vector_type(2))) unsigned uint2v;

__device__ inline short f2bf(float f) {
    __hip_bfloat16 h = __float2bfloat16(f);
    return *reinterpret_cast<short*>(&h);
}
__device__ inline float bf2f(short s) {
    unsigned u = ((unsigned)(unsigned short)s) << 16;
    return __uint_as_float(u);
}
// rounded (half-up) bf16 bits
__device__ inline short b16r(float f) {
    return (short)((__float_as_uint(f) + 0x8000u) >> 16);
}
// pack two floats -> (bf16(lo) | bf16(hi)<<16), round-half-up
__device__ inline unsigned pk2(float lo, float hi) {
    unsigned ul = __float_as_uint(lo) + 0x8000u;
    unsigned uh = __float_as_uint(hi) + 0x8000u;
    return __builtin_amdgcn_perm(uh, ul, 0x07060302u);
}
// neighbor-lane value (lane ^ 1) via DPP quad_perm [1,0,3,2]
__device__ inline float dppx1(float v) {
    return __int_as_float(__builtin_amdgcn_mov_dpp(__float_as_int(v), 0xB1, 0xF, 0xF, true));
}

// ---------------------------------------------------------------------------
// prep: wtf = stacked Wq|Wk|Wv^T B-frag file (q scaled 0.1*log2e, kd padded,
// zero pads); wotf = Wo^T B-frag file with k-axis = h*64+kd (rows kd>=50 zero).
// ---------------------------------------------------------------------------
#define N_WT  49152    // 384 n x 128 k
#define N_WOT 14336    // 112 n x 128 k
#define N_PREP (N_WT + N_WOT)

__global__ __launch_bounds__(256) void prep(
        const float* __restrict__ Wq, const float* __restrict__ Wk,
        const float* __restrict__ Wv, const float* __restrict__ Wo,
        short* __restrict__ wtf, short* __restrict__ wotf) {
    for (int i = blockIdx.x * 256 + threadIdx.x; i < N_PREP; i += gridDim.x * 256) {
        if (i < N_WT) {
            int n = i >> 7, k = i & 127;
            float val = 0.0f;
            if (k < DIN) {
                if (n < 256) {
                    int proj = n >> 7, h = (n >> 6) & 1, kk = n & 63;
                    if (kk < KR)
                        val = (proj ? Wk : Wq)[k * DIN + h * KR + kk] *
                              (proj ? 1.0f : 0.1f * LOG2E);
                } else {
                    int vv = n - 256, h = vv >> 6, kk = vv & 63;
                    if (kk < KR) val = Wv[k * DIN + h * KR + kk];
                }
            }
            int nb = n >> 4, n16 = n & 15, c = k >> 5, q2 = (k >> 3) & 3, j = k & 7;
            wtf[(((nb * 4 + c) * 64) + q2 * 16 + n16) * 8 + j] = f2bf(val);
        } else {
            int e = i - N_WT, n = e >> 7, k = e & 127;
            int h = k >> 6, kd = k & 63;
            float val = (n < DIN && kd < KR) ? Wo[(h * KR + kd) * DIN + n] : 0.0f;
            int nb = n >> 4, n16 = n & 15, c = k >> 5, q2 = (k >> 3) & 3, j = k & 7;
            wotf[(((nb * 4 + c) * 64) + q2 * 16 + n16) * 8 + j] = f2bf(val);
        }
    }
}

// ---------------------------------------------------------------------------
// qkv_gemm: x(fp32, perm-converted once) @ wt^T for 3 n-tiles per block.
// by: 0,1 = q(h0,h1); 2,3 = k(h0,h1); 4,5 = v(h0,h1). Epilogue repacks C
// via LDS into frag files; injects col 50 (q: log2e, k: mask, vT row50: 1.0).
// ---------------------------------------------------------------------------
__global__ __launch_bounds__(256) void qkv_gemm(
        const float* __restrict__ x, const short* __restrict__ wtf,
        const float* __restrict__ mask,
        short* __restrict__ qf, short* __restrict__ kf, short* __restrict__ vf) {
    __shared__ __align__(16) short xs[64 * 136];
    __shared__ __align__(16) short ls[64 * 72];
    const int m0 = blockIdx.x * 64;
    const int tid = threadIdx.x;
    const int wave = tid >> 6, lane = tid & 63, quad = lane >> 4, n16 = lane & 15;

    // ---- stage + convert x rows [m0, m0+64) ----
    {
        const int r = tid >> 2, seg = tid & 3;
        const float* xr = x + (size_t)(m0 + r) * DIN;
        if (seg < 3) {
#pragma unroll
            for (int q8 = 0; q8 < 4; q8++) {
                float4v a = *(const float4v*)(xr + seg * 32 + q8 * 8);
                float4v b = *(const float4v*)(xr + seg * 32 + q8 * 8 + 4);
                union { unsigned u[4]; short8 s; } t;
                t.u[0] = pk2(a[0], a[1]); t.u[1] = pk2(a[2], a[3]);
                t.u[2] = pk2(b[0], b[1]); t.u[3] = pk2(b[2], b[3]);
                *(short8*)&xs[r * 136 + seg * 32 + q8 * 8] = t.s;
            }
        } else {
            float4v a = *(const float4v*)(xr + 96);
            union { unsigned u[4]; short8 s; } t;
            t.u[0] = pk2(a[0], a[1]); t.u[1] = pk2(a[2], a[3]);
            t.u[2] = 0; t.u[3] = 0;
            *(short8*)&xs[r * 136 + 96] = t.s;
            short8 z = {0, 0, 0, 0, 0, 0, 0, 0};
            *(short8*)&xs[r * 136 + 104] = z;
            *(short8*)&xs[r * 136 + 112] = z;
            *(short8*)&xs[r * 136 + 120] = z;
        }
    }
    __syncthreads();

    // resident A-frags (wave's 16 rows)
    short8 xa[4];
#pragma unroll
    for (int ks = 0; ks < 4; ks++)
        xa[ks] = *(const short8*)&xs[(wave * 16 + n16) * 136 + ks * 32 + quad * 8];

    const int bi = m0 >> 11, tb0 = m0 & 2047;

    for (int bys = 0; bys < 3; bys++) {
        const int by = blockIdx.y * 3 + bys;
        float4v acc[4];
#pragma unroll
        for (int nt = 0; nt < 4; nt++) { acc[nt][0] = 0.f; acc[nt][1] = 0.f; acc[nt][2] = 0.f; acc[nt][3] = 0.f; }
#pragma unroll
        for (int ks = 0; ks < 4; ks++) {
#pragma unroll
            for (int nt = 0; nt < 4; nt++) {
                short8 bf = *(const short8*)&wtf[(((by * 4 + nt) * 4 + ks) * 64 + lane) * 8];
                acc[nt] = __builtin_amdgcn_mfma_f32_16x16x32_bf16(xa[ks], bf, acc[nt], 0, 0, 0);
            }
        }
        const int h = by & 1, bh = bi * NH + h;
        __syncthreads();   // ls free (prev tile's reads done)

        if (by < 4) {
            const bool isq = (by < 2);
            const float* mrow = mask + (size_t)(bh & 7) * SEQ + tb0;
#pragma unroll
            for (int nt = 0; nt < 4; nt++) {
#pragma unroll
                for (int r = 0; r < 4; r++) {
                    float val = acc[nt][r];
                    if (nt == 3 && n16 == 2)
                        val = isq ? LOG2E : mrow[wave * 16 + quad * 4 + r];
                    ls[(wave * 16 + quad * 4 + r) * 72 + nt * 16 + n16] = b16r(val);
                }
            }
            __syncthreads();
            short* dst = (isq ? qf : kf) + ((size_t)(bh * 128 + (tb0 >> 4) + wave) * 2) * 512;
#pragma unroll
            for (int c = 0; c < 2; c++)
                *(short8*)&dst[c * 512 + lane * 8] =
                    *(const short8*)&ls[(wave * 16 + n16) * 72 + c * 32 + quad * 8];
        } else {
            // v: transpose to ls[kd][t]; inject ones row kd=50
#pragma unroll
            for (int nt = 0; nt < 4; nt++) {
                float v0 = acc[nt][0], v1 = acc[nt][1], v2 = acc[nt][2], v3 = acc[nt][3];
                if (nt == 3 && n16 == 2) { v0 = 1.f; v1 = 1.f; v2 = 1.f; v3 = 1.f; }
                uint2v u; u[0] = pk2(v0, v1); u[1] = pk2(v2, v3);
                *(uint2v*)&ls[(nt * 16 + n16) * 72 + wave * 16 + quad * 4] = u;
            }
            __syncthreads();
            short* dst = vf + ((size_t)(bh * 4 + wave) * 64 + (tb0 >> 5)) * 512;
#pragma unroll
            for (int kc = 0; kc < 2; kc++)
                *(short8*)&dst[kc * 512 + lane * 8] =
                    *(const short8*)&ls[(wave * 16 + n16) * 72 + kc * 32 + quad * 8];
        }
        __syncthreads();
    }
}

// ---------------------------------------------------------------------------
// attn: max-free flash attention, 64 q-rows per wave (4 sets of 16), p =
// exp2(score) raw. Each iter: 16 frag loads (issued up front) feed 64 MFMAs.
// P writes DPP-packed. l rides PV col 50. Grid (BH, SEQ/256, S), block 256.
// ---------------------------------------------------------------------------
template <int S>
__global__ __launch_bounds__(256) void attn(
        const short* __restrict__ qf, const short* __restrict__ kf,
        const short* __restrict__ vf,
        short* __restrict__ o_part, float* __restrict__ lsum) {
    __shared__ __align__(16) short P[4][4][16 * 72];   // [wave][set]

    const int bh = blockIdx.x;
    const int t0 = blockIdx.y * 256;
    const int sp = blockIdx.z;
    const int KSPAN = SEQ / S;
    const int tid = threadIdx.x;
    const int wave = tid >> 6, lane = tid & 63, quad = lane >> 4, n16 = lane & 15;

    short8 qa[4][2];
#pragma unroll
    for (int s = 0; s < 4; s++) {
        const short* qfb = qf + ((size_t)(bh * 128 + (t0 >> 4) + wave * 4 + s) * 2) * 512;
        qa[s][0] = *(const short8*)&qfb[lane * 8];
        qa[s][1] = *(const short8*)&qfb[512 + lane * 8];
    }

    float4v oc[4][4];
#pragma unroll
    for (int s = 0; s < 4; s++)
#pragma unroll
        for (int nt = 0; nt < 4; nt++) { oc[s][nt][0] = 0.f; oc[s][nt][1] = 0.f; oc[s][nt][2] = 0.f; oc[s][nt][3] = 0.f; }

    const short* kfb = kf + (size_t)bh * 128 * 2 * 512;
    const short* vfb = vf + (size_t)bh * 4 * 64 * 512;

    // P write geometry (DPP-packed): even lane handles rows quad*4+{0,1} of
    // col-pair (n16&~1); odd lane rows quad*4+{2,3}.
    const int podd  = n16 & 1;
    const int prow  = quad * 4 + (podd ? 2 : 0);
    const int pcol  = n16 & ~1;

    for (int s0 = sp * KSPAN; s0 < sp * KSPAN + KSPAN; s0 += 64) {
        const int sb = s0 >> 4, kcb = s0 >> 5;
        short8 kfr[4][2], vfr[4][2];
#pragma unroll
        for (int jb = 0; jb < 4; jb++) {
#pragma unroll
            for (int c = 0; c < 2; c++)
                kfr[jb][c] = *(const short8*)&kfb[((sb + jb) * 2 + c) * 512 + lane * 8];
        }
#pragma unroll
        for (int nt = 0; nt < 4; nt++) {
#pragma unroll
            for (int kc = 0; kc < 2; kc++)
                vfr[nt][kc] = *(const short8*)&vfb[(nt * 64 + kcb + kc) * 512 + lane * 8];
        }

        // K phase: per set, scores -> exp2 -> DPP-packed P write (cf transient)
#pragma unroll
        for (int s = 0; s < 4; s++) {
            float4v cf[4];
#pragma unroll
            for (int jb = 0; jb < 4; jb++) {
                float4v z = {0.f, 0.f, 0.f, 0.f};
                z = __builtin_amdgcn_mfma_f32_16x16x32_bf16(qa[s][0], kfr[jb][0], z, 0, 0, 0);
                z = __builtin_amdgcn_mfma_f32_16x16x32_bf16(qa[s][1], kfr[jb][1], z, 0, 0, 0);
                cf[jb] = z;
            }
            short* Pw = &P[wave][s][0];
#pragma unroll
            for (int jb = 0; jb < 4; jb++) {
                float e0 = __builtin_amdgcn_exp2f(cf[jb][0]);
                float e1 = __builtin_amdgcn_exp2f(cf[jb][1]);
                float e2 = __builtin_amdgcn_exp2f(cf[jb][2]);
                float e3 = __builtin_amdgcn_exp2f(cf[jb][3]);
                float x0 = dppx1(e0), x1 = dppx1(e1), x2 = dppx1(e2), x3 = dppx1(e3);
                unsigned dwA = podd ? pk2(x2, e2) : pk2(e0, x0);
                unsigned dwB = podd ? pk2(x3, e3) : pk2(e1, x1);
                unsigned* pr = (unsigned*)&Pw[prow * 72 + jb * 16 + pcol];
                pr[0] = dwA;                                // row prow
                *(unsigned*)((char*)pr + 144) = dwB;        // row prow+1
            }
        }

        // V phase: per set, P read (A-frag) -> PV
#pragma unroll
        for (int s = 0; s < 4; s++) {
            const short* Pw = &P[wave][s][0];
            short8 pa0 = *(const short8*)&Pw[n16 * 72 + quad * 8];
            short8 pa1 = *(const short8*)&Pw[n16 * 72 + 32 + quad * 8];
#pragma unroll
            for (int nt = 0; nt < 4; nt++) {
                oc[s][nt] = __builtin_amdgcn_mfma_f32_16x16x32_bf16(pa0, vfr[nt][0], oc[s][nt], 0, 0, 0);
                oc[s][nt] = __builtin_amdgcn_mfma_f32_16x16x32_bf16(pa1, vfr[nt][1], oc[s][nt], 0, 0, 0);
            }
        }
    }

    // epilogue: l = PV col 50 (nt=3, n16==2); normalize; store O A-frag order.
#pragma unroll
    for (int s = 0; s < 4; s++) {
        float lv[4], linv[4];
#pragma unroll
        for (int r = 0; r < 4; r++) {
            lv[r] = __shfl(oc[s][3][r], quad * 16 + 2, 64);
            linv[r] = 1.0f / lv[r];
        }
        short* Pw = &P[wave][s][0];   // reuse as transform scratch (same wave)
#pragma unroll
        for (int nt = 0; nt < 4; nt++) {
#pragma unroll
            for (int r = 0; r < 4; r++)
                Pw[(quad * 4 + r) * 72 + nt * 16 + n16] = b16r(oc[s][nt][r] * linv[r]);
        }
        short* ob = o_part + ((size_t)((sp * BH + bh) * 128 + (t0 >> 4) + wave * 4 + s) * 2) * 512;
#pragma unroll
        for (int c = 0; c < 2; c++)
            *(short8*)&ob[c * 512 + lane * 8] =
                *(const short8*)&Pw[n16 * 72 + c * 32 + quad * 8];
        if (n16 == 0) {
#pragma unroll
            for (int r = 0; r < 4; r++)
                lsum[(size_t)(sp * BH + bh) * SEQ + t0 + wave * 64 + s * 16 + quad * 4 + r] = lv[r];
        }
    }
}

// ---------------------------------------------------------------------------
// out_proj: LDS-free. A-frags = l-weighted merge of o_part frag files
// (w_s = l_s / sum l_s), B = wotf, out = x + ctx@Wo + bo. Block 128.
// ---------------------------------------------------------------------------
template <int S>
__global__ __launch_bounds__(128) void out_proj(
        const float* __restrict__ x, const short* __restrict__ o_part,
        const float* __restrict__ lsum, const short* __restrict__ wotf,
        const float* __restrict__ bo, float* __restrict__ out) {
    const int g0 = blockIdx.x * 32;
    const int bi = g0 >> 11, tb = g0 & 2047;
    const int tid = threadIdx.x;
    const int wave = tid >> 6, lane = tid & 63, quad = lane >> 4, n16 = lane & 15;
    const int trow = tb + wave * 16 + n16;        // this lane's A row

    // merge coefficients per head: w_s = l_s / sum(l_s)
    float cs[2][S];
#pragma unroll
    for (int h = 0; h < 2; h++) {
        const int bh = bi * NH + h;
        float ll[S], wsum = 0.0f;
#pragma unroll
        for (int s = 0; s < S; s++) {
            ll[s] = lsum[(size_t)(s * BH + bh) * SEQ + trow];
            wsum += ll[s];
        }
        float inv = 1.0f / wsum;
#pragma unroll
        for (int s = 0; s < S; s++) cs[h][s] = ll[s] * inv;
    }

    // A-frags: merged o_part (k-axis = h*64+kd)
    const int rb = (tb >> 4) + wave;
    short8 af[4];
#pragma unroll
    for (int c = 0; c < 4; c++) {
        const int h = c >> 1, cc = c & 1, bh = bi * NH + h;
        float v[8];
#pragma unroll
        for (int j = 0; j < 8; j++) v[j] = 0.0f;
#pragma unroll
        for (int s = 0; s < S; s++) {
            const short* opb = o_part + ((size_t)((s * BH + bh) * 128 + rb) * 2 + cc) * 512;
            short8 f = *(const short8*)&opb[lane * 8];
            float w = cs[h][s];
#pragma unroll
            for (int j = 0; j < 8; j++) v[j] += w * bf2f(f[j]);
        }
        union { unsigned u[4]; short8 s8; } t;
#pragma unroll
        for (int p = 0; p < 4; p++) t.u[p] = pk2(v[2 * p], v[2 * p + 1]);
        af[c] = t.s8;
    }

    float4v acc[7];
#pragma unroll
    for (int nt = 0; nt < 7; nt++) { acc[nt][0] = 0.f; acc[nt][1] = 0.f; acc[nt][2] = 0.f; acc[nt][3] = 0.f; }
#pragma unroll
    for (int ks = 0; ks < 4; ks++) {
#pragma unroll
        for (int nt = 0; nt < 7; nt++) {
            short8 bf = *(const short8*)&wotf[((nt * 4 + ks) * 64 + lane) * 8];
            acc[nt] = __builtin_amdgcn_mfma_f32_16x16x32_bf16(af[ks], bf, acc[nt], 0, 0, 0);
        }
    }

#pragma unroll
    for (int nt = 0; nt < 7; nt++) {
        const int col = nt * 16 + n16;
        if (col < DIN) {
            float bv = bo[col];
#pragma unroll
            for (int r = 0; r < 4; r++) {
                int row = g0 + wave * 16 + quad * 4 + r;
                size_t idx = (size_t)row * DIN + col;
                out[idx] = x[idx] + acc[nt][r] + bv;
            }
        }
    }
}

// ---------------------------------------------------------------------------
extern "C" void kernel_launch(void* const* d_in, const int* in_sizes, int n_in,
                              void* d_out, int out_size, void* d_ws, size_t ws_size,
                              hipStream_t stream) {
    const float* x    = (const float*)d_in[0];
    const float* mask = (const float*)d_in[1];
    const float* Wq   = (const float*)d_in[2];
    const float* Wk   = (const float*)d_in[3];
    const float* Wv   = (const float*)d_in[4];
    const float* Wo   = (const float*)d_in[5];
    const float* bo   = (const float*)d_in[6];
    float* out = (float*)d_out;

    const size_t SZ_QKV = 3u * 4194304u;                 // qf+kf+vf
    const size_t SZ_OP1 = 4194304u;                      // o_part per split
    const size_t SZ_ML1 = (size_t)BH * SEQ * 4u;         // lsum per split
    const size_t SZ_W   = (size_t)N_WT * 2 + (size_t)N_WOT * 2;
    const size_t need8  = SZ_QKV + 8 * (SZ_OP1 + SZ_ML1) + SZ_W;
    const size_t need4  = SZ_QKV + 4 * (SZ_OP1 + SZ_ML1) + SZ_W;
    const int S = (ws_size >= need8 + 65536) ? 8
                : (ws_size >= need4 + 65536) ? 4 : 2;

    char* ws = (char*)d_ws;
    short*   qfp    = (short*)(ws);
    short*   kfp    = (short*)(ws + 4194304u);
    short*   vfp    = (short*)(ws + 8388608u);
    short*   o_part = (short*)(ws + SZ_QKV);
    float*   lsv    = (float*)(ws + SZ_QKV + (size_t)S * SZ_OP1);
    short*   wtf    = (short*)(ws + SZ_QKV + (size_t)S * (SZ_OP1 + SZ_ML1));
    short*   wotf   = wtf + N_WT;

    prep<<<128, 256, 0, stream>>>(Wq, Wk, Wv, Wo, wtf, wotf);
    qkv_gemm<<<dim3(256, 2), 256, 0, stream>>>(x, wtf, mask, qfp, kfp, vfp);
    if (S == 8) {
        attn<8><<<dim3(BH, SEQ / 256, 8), 256, 0, stream>>>(qfp, kfp, vfp, o_part, lsv);
        out_proj<8><<<512, 128, 0, stream>>>(x, o_part, lsv, wotf, bo, out);
    } else if (S == 4) {
        attn<4><<<dim3(BH, SEQ / 256, 4), 256, 0, stream>>>(qfp, kfp, vfp, o_part, lsv);
        out_proj<4><<<512, 128, 0, stream>>>(x, o_part, lsv, wotf, bo, out);
    } else {
        attn<2><<<dim3(BH, SEQ / 256, 2), 256, 0, stream>>>(qfp, kfp, vfp, o_part, lsv);
        out_proj<2><<<512, 128, 0, stream>>>(x, o_part, lsv, wotf, bo, out);
    }
}

// Round 10
// 114.489 us; speedup vs baseline: 1.1627x; 1.1627x over previous
//
#include <hip/hip_runtime.h>
#include <hip/hip_bf16.h>
#include <math.h>

// MultiAttention  B=8, T=2048, D=100, H=2, K=50
// out = x + attn(x) @ Wo + bo; scores += mask[(b*2+h)%8][s].
// R10: transposed QK (S^T = K.Q^T; A/B frag layouts are identical so operands
// just swap) so P exits MFMA with qrow on n16; PV A-frags are then gathered
// IN-REGISTER via ds_bpermute (16 independent ops, no LDS write->read
// dependency). 32 q-rows/wave, S=8, max-free exp2 softmax, l rides PV col 50.

#define BATCH 8
#define SEQ   2048
#define DIN   100
#define NH    2
#define KR    50
#define KD    64
#define BH    16
#define LOG2E 1.44269504f

typedef __attribute__((ext_vector_type(8))) short short8;
typedef __attribute__((ext_vector_type(4))) float float4v;
typedef __attribute__((ext_vector_type(4))) unsigned uint4v;
typedef __attribute__((ext_vector_type(2))) unsigned uint2v;

__device__ inline short f2bf(float f) {
    __hip_bfloat16 h = __float2bfloat16(f);
    return *reinterpret_cast<short*>(&h);
}
__device__ inline float bf2f(short s) {
    unsigned u = ((unsigned)(unsigned short)s) << 16;
    return __uint_as_float(u);
}
// rounded (half-up) bf16 bits
__device__ inline short b16r(float f) {
    return (short)((__float_as_uint(f) + 0x8000u) >> 16);
}
// pack two floats -> (bf16(lo) | bf16(hi)<<16), round-half-up
__device__ inline unsigned pk2(float lo, float hi) {
    unsigned ul = __float_as_uint(lo) + 0x8000u;
    unsigned uh = __float_as_uint(hi) + 0x8000u;
    return __builtin_amdgcn_perm(uh, ul, 0x07060302u);
}

// ---------------------------------------------------------------------------
// prep: wtf = stacked Wq|Wk|Wv^T B-frag file (q scaled 0.1*log2e, kd padded,
// zero pads); wotf = Wo^T B-frag file with k-axis = h*64+kd (rows kd>=50 zero).
// ---------------------------------------------------------------------------
#define N_WT  49152    // 384 n x 128 k
#define N_WOT 14336    // 112 n x 128 k
#define N_PREP (N_WT + N_WOT)

__global__ __launch_bounds__(256) void prep(
        const float* __restrict__ Wq, const float* __restrict__ Wk,
        const float* __restrict__ Wv, const float* __restrict__ Wo,
        short* __restrict__ wtf, short* __restrict__ wotf) {
    for (int i = blockIdx.x * 256 + threadIdx.x; i < N_PREP; i += gridDim.x * 256) {
        if (i < N_WT) {
            int n = i >> 7, k = i & 127;
            float val = 0.0f;
            if (k < DIN) {
                if (n < 256) {
                    int proj = n >> 7, h = (n >> 6) & 1, kk = n & 63;
                    if (kk < KR)
                        val = (proj ? Wk : Wq)[k * DIN + h * KR + kk] *
                              (proj ? 1.0f : 0.1f * LOG2E);
                } else {
                    int vv = n - 256, h = vv >> 6, kk = vv & 63;
                    if (kk < KR) val = Wv[k * DIN + h * KR + kk];
                }
            }
            int nb = n >> 4, n16 = n & 15, c = k >> 5, q2 = (k >> 3) & 3, j = k & 7;
            wtf[(((nb * 4 + c) * 64) + q2 * 16 + n16) * 8 + j] = f2bf(val);
        } else {
            int e = i - N_WT, n = e >> 7, k = e & 127;
            int h = k >> 6, kd = k & 63;
            float val = (n < DIN && kd < KR) ? Wo[(h * KR + kd) * DIN + n] : 0.0f;
            int nb = n >> 4, n16 = n & 15, c = k >> 5, q2 = (k >> 3) & 3, j = k & 7;
            wotf[(((nb * 4 + c) * 64) + q2 * 16 + n16) * 8 + j] = f2bf(val);
        }
    }
}

// ---------------------------------------------------------------------------
// qkv_gemm: x(fp32, perm-converted once) @ wt^T for 3 n-tiles per block.
// by: 0,1 = q(h0,h1); 2,3 = k(h0,h1); 4,5 = v(h0,h1). Epilogue repacks C
// via LDS into frag files; injects col 50 (q: log2e, k: mask, vT row50: 1.0).
// ---------------------------------------------------------------------------
__global__ __launch_bounds__(256) void qkv_gemm(
        const float* __restrict__ x, const short* __restrict__ wtf,
        const float* __restrict__ mask,
        short* __restrict__ qf, short* __restrict__ kf, short* __restrict__ vf) {
    __shared__ __align__(16) short xs[64 * 136];
    __shared__ __align__(16) short ls[64 * 72];
    const int m0 = blockIdx.x * 64;
    const int tid = threadIdx.x;
    const int wave = tid >> 6, lane = tid & 63, quad = lane >> 4, n16 = lane & 15;

    // ---- stage + convert x rows [m0, m0+64) ----
    {
        const int r = tid >> 2, seg = tid & 3;
        const float* xr = x + (size_t)(m0 + r) * DIN;
        if (seg < 3) {
#pragma unroll
            for (int q8 = 0; q8 < 4; q8++) {
                float4v a = *(const float4v*)(xr + seg * 32 + q8 * 8);
                float4v b = *(const float4v*)(xr + seg * 32 + q8 * 8 + 4);
                union { unsigned u[4]; short8 s; } t;
                t.u[0] = pk2(a[0], a[1]); t.u[1] = pk2(a[2], a[3]);
                t.u[2] = pk2(b[0], b[1]); t.u[3] = pk2(b[2], b[3]);
                *(short8*)&xs[r * 136 + seg * 32 + q8 * 8] = t.s;
            }
        } else {
            float4v a = *(const float4v*)(xr + 96);
            union { unsigned u[4]; short8 s; } t;
            t.u[0] = pk2(a[0], a[1]); t.u[1] = pk2(a[2], a[3]);
            t.u[2] = 0; t.u[3] = 0;
            *(short8*)&xs[r * 136 + 96] = t.s;
            short8 z = {0, 0, 0, 0, 0, 0, 0, 0};
            *(short8*)&xs[r * 136 + 104] = z;
            *(short8*)&xs[r * 136 + 112] = z;
            *(short8*)&xs[r * 136 + 120] = z;
        }
    }
    __syncthreads();

    // resident A-frags (wave's 16 rows)
    short8 xa[4];
#pragma unroll
    for (int ks = 0; ks < 4; ks++)
        xa[ks] = *(const short8*)&xs[(wave * 16 + n16) * 136 + ks * 32 + quad * 8];

    const int bi = m0 >> 11, tb0 = m0 & 2047;

    for (int bys = 0; bys < 3; bys++) {
        const int by = blockIdx.y * 3 + bys;
        float4v acc[4];
#pragma unroll
        for (int nt = 0; nt < 4; nt++) { acc[nt][0] = 0.f; acc[nt][1] = 0.f; acc[nt][2] = 0.f; acc[nt][3] = 0.f; }
#pragma unroll
        for (int ks = 0; ks < 4; ks++) {
#pragma unroll
            for (int nt = 0; nt < 4; nt++) {
                short8 bf = *(const short8*)&wtf[(((by * 4 + nt) * 4 + ks) * 64 + lane) * 8];
                acc[nt] = __builtin_amdgcn_mfma_f32_16x16x32_bf16(xa[ks], bf, acc[nt], 0, 0, 0);
            }
        }
        const int h = by & 1, bh = bi * NH + h;
        __syncthreads();   // ls free (prev tile's reads done)

        if (by < 4) {
            const bool isq = (by < 2);
            const float* mrow = mask + (size_t)(bh & 7) * SEQ + tb0;
#pragma unroll
            for (int nt = 0; nt < 4; nt++) {
#pragma unroll
                for (int r = 0; r < 4; r++) {
                    float val = acc[nt][r];
                    if (nt == 3 && n16 == 2)
                        val = isq ? LOG2E : mrow[wave * 16 + quad * 4 + r];
                    ls[(wave * 16 + quad * 4 + r) * 72 + nt * 16 + n16] = b16r(val);
                }
            }
            __syncthreads();
            short* dst = (isq ? qf : kf) + ((size_t)(bh * 128 + (tb0 >> 4) + wave) * 2) * 512;
#pragma unroll
            for (int c = 0; c < 2; c++)
                *(short8*)&dst[c * 512 + lane * 8] =
                    *(const short8*)&ls[(wave * 16 + n16) * 72 + c * 32 + quad * 8];
        } else {
            // v: transpose to ls[kd][t]; inject ones row kd=50
#pragma unroll
            for (int nt = 0; nt < 4; nt++) {
                float v0 = acc[nt][0], v1 = acc[nt][1], v2 = acc[nt][2], v3 = acc[nt][3];
                if (nt == 3 && n16 == 2) { v0 = 1.f; v1 = 1.f; v2 = 1.f; v3 = 1.f; }
                uint2v u; u[0] = pk2(v0, v1); u[1] = pk2(v2, v3);
                *(uint2v*)&ls[(nt * 16 + n16) * 72 + wave * 16 + quad * 4] = u;
            }
            __syncthreads();
            short* dst = vf + ((size_t)(bh * 4 + wave) * 64 + (tb0 >> 5)) * 512;
#pragma unroll
            for (int kc = 0; kc < 2; kc++)
                *(short8*)&dst[kc * 512 + lane * 8] =
                    *(const short8*)&ls[(wave * 16 + n16) * 72 + kc * 32 + quad * 8];
        }
        __syncthreads();
    }
}

// ---------------------------------------------------------------------------
// attn: transposed-QK flash attention, 32 q-rows/wave, max-free exp2 softmax.
// S^T = K.Q^T -> lane(n16,quad) holds P[qrow=n16][key=16jb+4quad+r]; pack
// key-pairs to dwords, gather PV A-frags via ds_bpermute (no LDS round-trip).
// l rides PV col 50. Grid (BH, SEQ/128, S), block 256.
// ---------------------------------------------------------------------------
template <int S>
__global__ __launch_bounds__(256) void attn(
        const short* __restrict__ qf, const short* __restrict__ kf,
        const short* __restrict__ vf,
        short* __restrict__ o_part, float* __restrict__ lsum) {
    __shared__ __align__(16) short Pep[4][2][16 * 72];   // epilogue scratch only

    const int bh = blockIdx.x;
    const int t0 = blockIdx.y * 128;
    const int sp = blockIdx.z;
    const int KSPAN = SEQ / S;
    const int tid = threadIdx.x;
    const int wave = tid >> 6, lane = tid & 63, quad = lane >> 4, n16 = lane & 15;

    short8 qa[2][2];
#pragma unroll
    for (int s = 0; s < 2; s++) {
        const short* qfb = qf + ((size_t)(bh * 128 + (t0 >> 4) + wave * 2 + s) * 2) * 512;
        qa[s][0] = *(const short8*)&qfb[lane * 8];
        qa[s][1] = *(const short8*)&qfb[512 + lane * 8];
    }

    float4v oc[2][4];
#pragma unroll
    for (int s = 0; s < 2; s++)
#pragma unroll
        for (int nt = 0; nt < 4; nt++) { oc[s][nt][0] = 0.f; oc[s][nt][1] = 0.f; oc[s][nt][2] = 0.f; oc[s][nt][3] = 0.f; }

    const short* kfb = kf + (size_t)bh * 128 * 2 * 512;
    const short* vfb = vf + (size_t)bh * 4 * 64 * 512;

    // bpermute indices (bytes): dw0/1 source lane = n16 + 32*(quad&1);
    // dw2/3 source lane = +16.
    const int idxA = (n16 + 32 * (quad & 1)) * 4;
    const int idxB = idxA + 64;
    const bool hiq = (quad >= 2);

    for (int s0 = sp * KSPAN; s0 < sp * KSPAN + KSPAN; s0 += 64) {
        const int sb = s0 >> 4, kcb = s0 >> 5;
        short8 kfr[4][2], vfr[4][2];
#pragma unroll
        for (int jb = 0; jb < 4; jb++) {
#pragma unroll
            for (int c = 0; c < 2; c++)
                kfr[jb][c] = *(const short8*)&kfb[((sb + jb) * 2 + c) * 512 + lane * 8];
        }
#pragma unroll
        for (int nt = 0; nt < 4; nt++) {
#pragma unroll
            for (int kc = 0; kc < 2; kc++)
                vfr[nt][kc] = *(const short8*)&vfb[(nt * 64 + kcb + kc) * 512 + lane * 8];
        }

#pragma unroll
        for (int s = 0; s < 2; s++) {
            // S^T tiles: A = K frags, B = Q frags (identical lane layouts)
            float4v cf[4];
#pragma unroll
            for (int jb = 0; jb < 4; jb++) {
                float4v z = {0.f, 0.f, 0.f, 0.f};
                z = __builtin_amdgcn_mfma_f32_16x16x32_bf16(kfr[jb][0], qa[s][0], z, 0, 0, 0);
                z = __builtin_amdgcn_mfma_f32_16x16x32_bf16(kfr[jb][1], qa[s][1], z, 0, 0, 0);
                cf[jb] = z;
            }
            // p = exp2(score); pack key-pairs: d[jb][p] = keys 16jb+4quad+2p,+1
            unsigned d[4][2];
#pragma unroll
            for (int jb = 0; jb < 4; jb++) {
                float e0 = __builtin_amdgcn_exp2f(cf[jb][0]);
                float e1 = __builtin_amdgcn_exp2f(cf[jb][1]);
                float e2 = __builtin_amdgcn_exp2f(cf[jb][2]);
                float e3 = __builtin_amdgcn_exp2f(cf[jb][3]);
                d[jb][0] = pk2(e0, e1);
                d[jb][1] = pk2(e2, e3);
            }
            // gather A-frags for PV via bpermute (quads 0,1 take jb_lo; 2,3 jb_hi)
            union { uint4v u; short8 s8; } pa0, pa1;
            {
                unsigned a0 = __builtin_amdgcn_ds_bpermute(idxA, d[0][0]);
                unsigned b0 = __builtin_amdgcn_ds_bpermute(idxA, d[1][0]);
                unsigned a1 = __builtin_amdgcn_ds_bpermute(idxA, d[0][1]);
                unsigned b1 = __builtin_amdgcn_ds_bpermute(idxA, d[1][1]);
                unsigned a2 = __builtin_amdgcn_ds_bpermute(idxB, d[0][0]);
                unsigned b2 = __builtin_amdgcn_ds_bpermute(idxB, d[1][0]);
                unsigned a3 = __builtin_amdgcn_ds_bpermute(idxB, d[0][1]);
                unsigned b3 = __builtin_amdgcn_ds_bpermute(idxB, d[1][1]);
                pa0.u[0] = hiq ? b0 : a0;
                pa0.u[1] = hiq ? b1 : a1;
                pa0.u[2] = hiq ? b2 : a2;
                pa0.u[3] = hiq ? b3 : a3;
            }
            {
                unsigned a0 = __builtin_amdgcn_ds_bpermute(idxA, d[2][0]);
                unsigned b0 = __builtin_amdgcn_ds_bpermute(idxA, d[3][0]);
                unsigned a1 = __builtin_amdgcn_ds_bpermute(idxA, d[2][1]);
                unsigned b1 = __builtin_amdgcn_ds_bpermute(idxA, d[3][1]);
                unsigned a2 = __builtin_amdgcn_ds_bpermute(idxB, d[2][0]);
                unsigned b2 = __builtin_amdgcn_ds_bpermute(idxB, d[3][0]);
                unsigned a3 = __builtin_amdgcn_ds_bpermute(idxB, d[2][1]);
                unsigned b3 = __builtin_amdgcn_ds_bpermute(idxB, d[3][1]);
                pa1.u[0] = hiq ? b0 : a0;
                pa1.u[1] = hiq ? b1 : a1;
                pa1.u[2] = hiq ? b2 : a2;
                pa1.u[3] = hiq ? b3 : a3;
            }
            // PV: O += P.V (A = gathered P frags, B = V^T frags)
#pragma unroll
            for (int nt = 0; nt < 4; nt++) {
                oc[s][nt] = __builtin_amdgcn_mfma_f32_16x16x32_bf16(pa0.s8, vfr[nt][0], oc[s][nt], 0, 0, 0);
                oc[s][nt] = __builtin_amdgcn_mfma_f32_16x16x32_bf16(pa1.s8, vfr[nt][1], oc[s][nt], 0, 0, 0);
            }
        }
    }

    // epilogue: l = PV col 50 (nt=3, n16==2); normalize; store O A-frag order.
#pragma unroll
    for (int s = 0; s < 2; s++) {
        float lv[4], linv[4];
#pragma unroll
        for (int r = 0; r < 4; r++) {
            lv[r] = __shfl(oc[s][3][r], quad * 16 + 2, 64);
            linv[r] = 1.0f / lv[r];
        }
        short* Pw = &Pep[wave][s][0];
#pragma unroll
        for (int nt = 0; nt < 4; nt++) {
#pragma unroll
            for (int r = 0; r < 4; r++)
                Pw[(quad * 4 + r) * 72 + nt * 16 + n16] = b16r(oc[s][nt][r] * linv[r]);
        }
        short* ob = o_part + ((size_t)((sp * BH + bh) * 128 + (t0 >> 4) + wave * 2 + s) * 2) * 512;
#pragma unroll
        for (int c = 0; c < 2; c++)
            *(short8*)&ob[c * 512 + lane * 8] =
                *(const short8*)&Pw[n16 * 72 + c * 32 + quad * 8];
        if (n16 == 0) {
#pragma unroll
            for (int r = 0; r < 4; r++)
                lsum[(size_t)(sp * BH + bh) * SEQ + t0 + wave * 32 + s * 16 + quad * 4 + r] = lv[r];
        }
    }
}

// ---------------------------------------------------------------------------
// out_proj: LDS-free. A-frags = l-weighted merge of o_part frag files
// (w_s = l_s / sum l_s), B = wotf, out = x + ctx@Wo + bo. Block 128.
// ---------------------------------------------------------------------------
template <int S>
__global__ __launch_bounds__(128) void out_proj(
        const float* __restrict__ x, const short* __restrict__ o_part,
        const float* __restrict__ lsum, const short* __restrict__ wotf,
        const float* __restrict__ bo, float* __restrict__ out) {
    const int g0 = blockIdx.x * 32;
    const int bi = g0 >> 11, tb = g0 & 2047;
    const int tid = threadIdx.x;
    const int wave = tid >> 6, lane = tid & 63, quad = lane >> 4, n16 = lane & 15;
    const int trow = tb + wave * 16 + n16;        // this lane's A row

    // merge coefficients per head: w_s = l_s / sum(l_s)
    float cs[2][S];
#pragma unroll
    for (int h = 0; h < 2; h++) {
        const int bh = bi * NH + h;
        float ll[S], wsum = 0.0f;
#pragma unroll
        for (int s = 0; s < S; s++) {
            ll[s] = lsum[(size_t)(s * BH + bh) * SEQ + trow];
            wsum += ll[s];
        }
        float inv = 1.0f / wsum;
#pragma unroll
        for (int s = 0; s < S; s++) cs[h][s] = ll[s] * inv;
    }

    // A-frags: merged o_part (k-axis = h*64+kd)
    const int rb = (tb >> 4) + wave;
    short8 af[4];
#pragma unroll
    for (int c = 0; c < 4; c++) {
        const int h = c >> 1, cc = c & 1, bh = bi * NH + h;
        float v[8];
#pragma unroll
        for (int j = 0; j < 8; j++) v[j] = 0.0f;
#pragma unroll
        for (int s = 0; s < S; s++) {
            const short* opb = o_part + ((size_t)((s * BH + bh) * 128 + rb) * 2 + cc) * 512;
            short8 f = *(const short8*)&opb[lane * 8];
            float w = cs[h][s];
#pragma unroll
            for (int j = 0; j < 8; j++) v[j] += w * bf2f(f[j]);
        }
        union { unsigned u[4]; short8 s8; } t;
#pragma unroll
        for (int p = 0; p < 4; p++) t.u[p] = pk2(v[2 * p], v[2 * p + 1]);
        af[c] = t.s8;
    }

    float4v acc[7];
#pragma unroll
    for (int nt = 0; nt < 7; nt++) { acc[nt][0] = 0.f; acc[nt][1] = 0.f; acc[nt][2] = 0.f; acc[nt][3] = 0.f; }
#pragma unroll
    for (int ks = 0; ks < 4; ks++) {
#pragma unroll
        for (int nt = 0; nt < 7; nt++) {
            short8 bf = *(const short8*)&wotf[((nt * 4 + ks) * 64 + lane) * 8];
            acc[nt] = __builtin_amdgcn_mfma_f32_16x16x32_bf16(af[ks], bf, acc[nt], 0, 0, 0);
        }
    }

#pragma unroll
    for (int nt = 0; nt < 7; nt++) {
        const int col = nt * 16 + n16;
        if (col < DIN) {
            float bv = bo[col];
#pragma unroll
            for (int r = 0; r < 4; r++) {
                int row = g0 + wave * 16 + quad * 4 + r;
                size_t idx = (size_t)row * DIN + col;
                out[idx] = x[idx] + acc[nt][r] + bv;
            }
        }
    }
}

// ---------------------------------------------------------------------------
extern "C" void kernel_launch(void* const* d_in, const int* in_sizes, int n_in,
                              void* d_out, int out_size, void* d_ws, size_t ws_size,
                              hipStream_t stream) {
    const float* x    = (const float*)d_in[0];
    const float* mask = (const float*)d_in[1];
    const float* Wq   = (const float*)d_in[2];
    const float* Wk   = (const float*)d_in[3];
    const float* Wv   = (const float*)d_in[4];
    const float* Wo   = (const float*)d_in[5];
    const float* bo   = (const float*)d_in[6];
    float* out = (float*)d_out;

    const size_t SZ_QKV = 3u * 4194304u;                 // qf+kf+vf
    const size_t SZ_OP1 = 4194304u;                      // o_part per split
    const size_t SZ_ML1 = (size_t)BH * SEQ * 4u;         // lsum per split
    const size_t SZ_W   = (size_t)N_WT * 2 + (size_t)N_WOT * 2;
    const size_t need8  = SZ_QKV + 8 * (SZ_OP1 + SZ_ML1) + SZ_W;
    const size_t need4  = SZ_QKV + 4 * (SZ_OP1 + SZ_ML1) + SZ_W;
    const int S = (ws_size >= need8 + 65536) ? 8
                : (ws_size >= need4 + 65536) ? 4 : 2;

    char* ws = (char*)d_ws;
    short*   qfp    = (short*)(ws);
    short*   kfp    = (short*)(ws + 4194304u);
    short*   vfp    = (short*)(ws + 8388608u);
    short*   o_part = (short*)(ws + SZ_QKV);
    float*   lsv    = (float*)(ws + SZ_QKV + (size_t)S * SZ_OP1);
    short*   wtf    = (short*)(ws + SZ_QKV + (size_t)S * (SZ_OP1 + SZ_ML1));
    short*   wotf   = wtf + N_WT;

    prep<<<128, 256, 0, stream>>>(Wq, Wk, Wv, Wo, wtf, wotf);
    qkv_gemm<<<dim3(256, 2), 256, 0, stream>>>(x, wtf, mask, qfp, kfp, vfp);
    if (S == 8) {
        attn<8><<<dim3(BH, SEQ / 128, 8), 256, 0, stream>>>(qfp, kfp, vfp, o_part, lsv);
        out_proj<8><<<512, 128, 0, stream>>>(x, o_part, lsv, wotf, bo, out);
    } else if (S == 4) {
        attn<4><<<dim3(BH, SEQ / 128, 4), 256, 0, stream>>>(qfp, kfp, vfp, o_part, lsv);
        out_proj<4><<<512, 128, 0, stream>>>(x, o_part, lsv, wotf, bo, out);
    } else {
        attn<2><<<dim3(BH, SEQ / 128, 2), 256, 0, stream>>>(qfp, kfp, vfp, o_part, lsv);
        out_proj<2><<<512, 128, 0, stream>>>(x, o_part, lsv, wotf, bo, out);
    }
}